// Round 10
// baseline (1113.837 us; speedup 1.0000x reference)
//
#include <hip/hip_runtime.h>
#include <stdint.h>

#define T_TOK 8192
#define H_DIM 1024
#define I_DIM 2752
#define E_NUM 8

typedef unsigned short ushort_t;
typedef short bf16x8 __attribute__((ext_vector_type(8)));
typedef float f32x16 __attribute__((ext_vector_type(16)));

__device__ __forceinline__ unsigned short f2bf(float f){
  union { float f; uint32_t u; } v; v.f = f;
  return (unsigned short)((v.u + 0x7fffu + ((v.u >> 16) & 1u)) >> 16);
}

__device__ __forceinline__ void gload16(const ushort_t* g, ushort_t* l){
  __builtin_amdgcn_global_load_lds(
      (const __attribute__((address_space(1))) void*)g,
      (__attribute__((address_space(3))) void*)l, 16, 0, 0);
}

// ---------------- convert fp32 -> bf16 ----------------
__global__ void cvt_kernel(const float4* __restrict__ src, ushort4* __restrict__ dst, int n4){
  int stride = gridDim.x * blockDim.x;
  for (int i = blockIdx.x * blockDim.x + threadIdx.x; i < n4; i += stride){
    float4 v = src[i];
    ushort4 o;
    o.x = f2bf(v.x); o.y = f2bf(v.y); o.z = f2bf(v.z); o.w = f2bf(v.w);
    dst[i] = o;
  }
}

__global__ void fill_kernel(float* __restrict__ p, float v, int n){
  int i = blockIdx.x * blockDim.x + threadIdx.x;
  if (i < n) p[i] = v;
}

// ---------------- gate: fp32 logits, softmax-top2; also emits x in bf16 ----------------
__global__ void gate_kernel(const float* __restrict__ x, const float* __restrict__ gw,
                            ushort_t* __restrict__ xb,
                            int* __restrict__ topk_idx, float* __restrict__ topk_w,
                            int* __restrict__ counts){
  int lane = threadIdx.x & 63;
  int wv = threadIdx.x >> 6;
  int t = blockIdx.x * 4 + wv;
  const float* xt = x + (size_t)t * H_DIM;
  ushort_t* xbt = xb + (size_t)t * H_DIM;
  float acc[E_NUM];
  #pragma unroll
  for (int e = 0; e < E_NUM; e++) acc[e] = 0.f;
  for (int c = 0; c < H_DIM / 64; c++){
    float xv = xt[c * 64 + lane];
    xbt[c * 64 + lane] = f2bf(xv);
    #pragma unroll
    for (int e = 0; e < E_NUM; e++) acc[e] += xv * gw[e * H_DIM + c * 64 + lane];
  }
  #pragma unroll
  for (int e = 0; e < E_NUM; e++){
    #pragma unroll
    for (int o = 32; o; o >>= 1) acc[e] += __shfl_xor(acc[e], o);
  }
  if (lane == 0){
    int i1 = 0; float l1 = acc[0];
    #pragma unroll
    for (int e = 1; e < E_NUM; e++) if (acc[e] > l1){ l1 = acc[e]; i1 = e; }
    int i2 = -1; float l2 = -1e30f;
    #pragma unroll
    for (int e = 0; e < E_NUM; e++) if (e != i1 && acc[e] > l2){ l2 = acc[e]; i2 = e; }
    float e2 = expf(l2 - l1);
    float denom = 1.0f + e2;
    topk_idx[t * 2 + 0] = i1; topk_idx[t * 2 + 1] = i2;
    topk_w[t * 2 + 0] = 1.0f / denom; topk_w[t * 2 + 1] = e2 / denom;
    atomicAdd(&counts[i1], 1); atomicAdd(&counts[i2], 1);
  }
}

__global__ void offsets_kernel(const int* __restrict__ counts, int* __restrict__ offs,
                               int* __restrict__ cursor){
  if (threadIdx.x == 0 && blockIdx.x == 0){
    int a = 0;
    for (int e = 0; e < E_NUM; e++){ offs[e] = a; cursor[e] = a; a += counts[e]; }
    offs[E_NUM] = a;
  }
}

__global__ void scatter_kernel(const int* __restrict__ topk_idx, const float* __restrict__ topk_w,
                               int* __restrict__ cursor, int* __restrict__ perm,
                               float* __restrict__ pw){
  int t = blockIdx.x * blockDim.x + threadIdx.x;
  if (t >= T_TOK) return;
  #pragma unroll
  for (int k = 0; k < 2; k++){
    int e = topk_idx[t * 2 + k];
    int pos = atomicAdd(&cursor[e], 1);
    perm[pos] = t;
    pw[pos] = topk_w[t * 2 + k];
  }
}

// helper: resolve grouped tile (BM=256)
__device__ __forceinline__ bool resolve_tile(const int* offs, int fixedM, int bx,
                                             int& e, int& row0, int& mEnd, int& maxRow){
  e = 0; row0 = 0; mEnd = fixedM; maxRow = fixedM - 1;
  if (offs){
    int base = 0; bool found = false;
    for (e = 0; e < E_NUM; ++e){
      int m0 = offs[e], m1 = offs[e + 1];
      int nt = (m1 - m0 + 255) >> 8;
      if (bx < base + nt){ row0 = m0 + (bx - base) * 256; mEnd = m1; found = true; break; }
      base += nt;
    }
    if (!found) return false;
    maxRow = offs[E_NUM] - 1;
    if (maxRow < 0) return false;
  } else {
    row0 = bx * 256;
  }
  return true;
}

// ---------------- GEMM1: h = silu(X@Wg^T) * (X@Wu^T) * route_w ----------------
// r5 schedule (best verified): BM=256 x BN=128 (dual B), BK=64, 8 waves 4Mx2N,
// 2-deep ring, full-tile prefetch + vmcnt(8), 2 barriers/K-tile, T2 swizzle.
// NEW: 32x32x16 MFMA (2x FLOP/instr, -17% matrix-pipe cycles).
__global__ __launch_bounds__(512, 2) void gemm1_kernel(
    const ushort_t* __restrict__ Xb,
    const ushort_t* __restrict__ Wg,
    const ushort_t* __restrict__ Wu,
    ushort_t* __restrict__ Hb,
    const int* __restrict__ offs,
    const int* __restrict__ perm,
    const float* __restrict__ pw,
    int fixedM)
{
  __shared__ __align__(16) ushort_t ldsA[2 * 16384];
  __shared__ __align__(16) ushort_t ldsG[2 * 8192];
  __shared__ __align__(16) ushort_t ldsU[2 * 8192];

  const int tid = threadIdx.x;
  const int lane = tid & 63;
  const int wv = tid >> 6;        // 0..7
  const int wm = wv >> 1;         // 0..3 (64-row band)
  const int wn = wv & 1;          // 0..1 (64-col band)

  int e, row0, mEnd, maxRow;
  if (!resolve_tile(offs, fixedM, blockIdx.y, e, row0, mEnd, maxRow)) return;

  const ushort_t* Weg = Wg + (size_t)e * I_DIM * H_DIM;
  const ushort_t* Weu = Wu + (size_t)e * I_DIM * H_DIM;
  const int nb = blockIdx.x * 128;

  // staging: 512 threads x 16B; issue i covers rows i*64..i*64+63
  const int sr = tid >> 3;                   // row-in-issue 0..63
  const int sc = (tid & 7) ^ (sr & 7);       // swizzled source chunk
  const ushort_t* sA[4];
  const ushort_t* sG[2];
  const ushort_t* sU[2];
  #pragma unroll
  for (int i = 0; i < 4; i++){
    int gr = row0 + i * 64 + sr;
    if (gr > maxRow) gr = maxRow;
    int tok = perm ? perm[gr] : gr;
    sA[i] = Xb + (size_t)tok * H_DIM + sc * 8;
  }
  #pragma unroll
  for (int i = 0; i < 2; i++){
    int n = nb + i * 64 + sr;
    if (n > I_DIM - 1) n = I_DIM - 1;
    sG[i] = Weg + (size_t)n * H_DIM + sc * 8;
    sU[i] = Weu + (size_t)n * H_DIM + sc * 8;
  }
  const int dstOff = wv * 512;

  // read-side addressing for 32x32x16 fragments:
  // lane holds row/col = lane&31, k = ks*16 + (lane>>5)*8
  // chunk = ks*2 + (lane>>5); swizzled by XOR with row&7 == lane&7
  int kx[4];
  #pragma unroll
  for (int ks = 0; ks < 4; ks++)
    kx[ks] = ((((ks << 1) | (lane >> 5)) ^ (lane & 7)) << 3);
  const int rowA = (wm * 64 + (lane & 31)) * 64;   // + mf*32*64
  const int rowB = (wn * 64 + (lane & 31)) * 64;   // + nf*32*64

  f32x16 accg[2][2], accu[2][2];
  #pragma unroll
  for (int m = 0; m < 2; m++)
    #pragma unroll
    for (int n = 0; n < 2; n++){
      accg[m][n] = (f32x16)(0.f);
      accu[m][n] = (f32x16)(0.f);
    }

  constexpr int NT = H_DIM / 64;   // 16

  // prologue: stage tile 0 -> slot 0
  #pragma unroll
  for (int i = 0; i < 4; i++) gload16(sA[i], ldsA + i * 4096 + dstOff);
  #pragma unroll
  for (int i = 0; i < 2; i++) gload16(sG[i], ldsG + i * 4096 + dstOff);
  #pragma unroll
  for (int i = 0; i < 2; i++) gload16(sU[i], ldsU + i * 4096 + dstOff);

  #pragma unroll 1
  for (int t = 0; t < NT; ++t){
    const int t1 = (t + 1 < NT) ? t + 1 : NT - 1;
    const int k1 = t1 * 64;
    const int sel  = (t & 1);
    const int sel1 = sel ^ 1;

    #pragma unroll
    for (int i = 0; i < 4; i++) gload16(sA[i] + k1, ldsA + sel1 * 16384 + i * 4096 + dstOff);
    #pragma unroll
    for (int i = 0; i < 2; i++) gload16(sG[i] + k1, ldsG + sel1 * 8192 + i * 4096 + dstOff);
    #pragma unroll
    for (int i = 0; i < 2; i++) gload16(sU[i] + k1, ldsU + sel1 * 8192 + i * 4096 + dstOff);

    asm volatile("s_waitcnt vmcnt(8)" ::: "memory");
    __builtin_amdgcn_s_barrier();
    __builtin_amdgcn_sched_barrier(0);

    const ushort_t* pA = ldsA + sel * 16384 + rowA;
    const ushort_t* pG = ldsG + sel * 8192 + rowB;
    const ushort_t* pU = ldsU + sel * 8192 + rowB;

    bf16x8 a[2], bg[2], bu[2];
    #pragma unroll
    for (int ks = 0; ks < 4; ks++){
      const int x = kx[ks];
      #pragma unroll
      for (int m = 0; m < 2; m++) a[m]  = *(const bf16x8*)(pA + m * 2048 + x);
      #pragma unroll
      for (int n = 0; n < 2; n++) bg[n] = *(const bf16x8*)(pG + n * 2048 + x);
      #pragma unroll
      for (int n = 0; n < 2; n++) bu[n] = *(const bf16x8*)(pU + n * 2048 + x);
      __builtin_amdgcn_s_setprio(1);
      #pragma unroll
      for (int m = 0; m < 2; m++)
        #pragma unroll
        for (int n = 0; n < 2; n++){
          accg[m][n] = __builtin_amdgcn_mfma_f32_32x32x16_bf16(a[m], bg[n], accg[m][n], 0, 0, 0);
          accu[m][n] = __builtin_amdgcn_mfma_f32_32x32x16_bf16(a[m], bu[n], accu[m][n], 0, 0, 0);
        }
      __builtin_amdgcn_s_setprio(0);
    }
    __builtin_amdgcn_s_barrier();
  }
  asm volatile("s_waitcnt vmcnt(0)" ::: "memory");

  // epilogue: silu(g)*u*wt -> bf16 h
  // C/D 32x32: col=lane&31, row=(r&3)+8*(r>>2)+4*(lane>>5)
  #pragma unroll
  for (int mf = 0; mf < 2; mf++){
    #pragma unroll
    for (int nf = 0; nf < 2; nf++){
      const int col = nb + wn * 64 + nf * 32 + (lane & 31);
      if (col < I_DIM){
        #pragma unroll
        for (int r = 0; r < 16; r++){
          int gr = row0 + wm * 64 + mf * 32 + (r & 3) + 8 * (r >> 2) + 4 * (lane >> 5);
          if (gr < mEnd){
            float wt = pw ? pw[gr] : 1.0f;
            float gv = accg[mf][nf][r];
            float uv = accu[mf][nf][r];
            float hv = (gv / (1.0f + __expf(-gv))) * uv * wt;
            Hb[(size_t)gr * I_DIM + col] = f2bf(hv);
          }
        }
      }
    }
  }
}

// ---------------- GEMM2: y[tok] (+)= h @ Wd^T ----------------
// BM=256 x BN=256, BK=64, 8 waves 2Mx4N, r5 schedule, 32x32x16 MFMA.
__global__ __launch_bounds__(512, 2) void gemm2_kernel(
    const ushort_t* __restrict__ Hb,
    const ushort_t* __restrict__ Wd,
    float* __restrict__ Y,
    const int* __restrict__ offs,
    const int* __restrict__ perm,
    int fixedM, int doAtomic)
{
  __shared__ __align__(16) ushort_t ldsA[2 * 16384];
  __shared__ __align__(16) ushort_t ldsB[2 * 16384];

  const int tid = threadIdx.x;
  const int lane = tid & 63;
  const int wv = tid >> 6;
  const int wm = wv >> 2;          // 0..1 (128-row band)
  const int wn = wv & 3;           // 0..3 (64-col band)

  int e, row0, mEnd, maxRow;
  if (!resolve_tile(offs, fixedM, blockIdx.y, e, row0, mEnd, maxRow)) return;

  const ushort_t* Wde = Wd + (size_t)e * H_DIM * I_DIM;
  const int nb = blockIdx.x * 256;

  const int sr = tid >> 3;
  const int sc = (tid & 7) ^ (sr & 7);
  const ushort_t* sA[4];
  const ushort_t* sB[4];
  #pragma unroll
  for (int i = 0; i < 4; i++){
    int gr = row0 + i * 64 + sr;
    if (gr > maxRow) gr = maxRow;
    sA[i] = Hb + (size_t)gr * I_DIM + sc * 8;
    int n = nb + i * 64 + sr;      // < 1024 always
    sB[i] = Wde + (size_t)n * I_DIM + sc * 8;
  }
  const int dstOff = wv * 512;

  int kx[4];
  #pragma unroll
  for (int ks = 0; ks < 4; ks++)
    kx[ks] = ((((ks << 1) | (lane >> 5)) ^ (lane & 7)) << 3);
  const int rowA = (wm * 128 + (lane & 31)) * 64;  // + mf*32*64
  const int rowB = (wn * 64 + (lane & 31)) * 64;   // + nf*32*64

  f32x16 acc[4][2];
  #pragma unroll
  for (int m = 0; m < 4; m++)
    #pragma unroll
    for (int n = 0; n < 2; n++) acc[m][n] = (f32x16)(0.f);

  constexpr int NT = I_DIM / 64;   // 43

  #pragma unroll
  for (int i = 0; i < 4; i++) gload16(sA[i], ldsA + i * 4096 + dstOff);
  #pragma unroll
  for (int i = 0; i < 4; i++) gload16(sB[i], ldsB + i * 4096 + dstOff);

  #pragma unroll 1
  for (int t = 0; t < NT; ++t){
    const int t1 = (t + 1 < NT) ? t + 1 : NT - 1;
    const int k1 = t1 * 64;
    const int sel  = (t & 1);
    const int sel1 = sel ^ 1;

    #pragma unroll
    for (int i = 0; i < 4; i++) gload16(sA[i] + k1, ldsA + sel1 * 16384 + i * 4096 + dstOff);
    #pragma unroll
    for (int i = 0; i < 4; i++) gload16(sB[i] + k1, ldsB + sel1 * 16384 + i * 4096 + dstOff);

    asm volatile("s_waitcnt vmcnt(8)" ::: "memory");
    __builtin_amdgcn_s_barrier();
    __builtin_amdgcn_sched_barrier(0);

    const ushort_t* pA = ldsA + sel * 16384 + rowA;
    const ushort_t* pB = ldsB + sel * 16384 + rowB;

    bf16x8 a[4], b[2];
    #pragma unroll
    for (int ks = 0; ks < 4; ks++){
      const int x = kx[ks];
      #pragma unroll
      for (int m = 0; m < 4; m++) a[m] = *(const bf16x8*)(pA + m * 2048 + x);
      #pragma unroll
      for (int n = 0; n < 2; n++) b[n] = *(const bf16x8*)(pB + n * 2048 + x);
      __builtin_amdgcn_s_setprio(1);
      #pragma unroll
      for (int m = 0; m < 4; m++)
        #pragma unroll
        for (int n = 0; n < 2; n++)
          acc[m][n] = __builtin_amdgcn_mfma_f32_32x32x16_bf16(a[m], b[n], acc[m][n], 0, 0, 0);
      __builtin_amdgcn_s_setprio(0);
    }
    __builtin_amdgcn_s_barrier();
  }
  asm volatile("s_waitcnt vmcnt(0)" ::: "memory");

  #pragma unroll
  for (int mf = 0; mf < 4; mf++){
    #pragma unroll
    for (int nf = 0; nf < 2; nf++){
      const int col = nb + wn * 64 + nf * 32 + (lane & 31);
      #pragma unroll
      for (int r = 0; r < 16; r++){
        int gr = row0 + wm * 128 + mf * 32 + (r & 3) + 8 * (r >> 2) + 4 * (lane >> 5);
        if (gr < mEnd){
          int tok = perm ? perm[gr] : gr;
          float v = acc[mf][nf][r];
          if (doAtomic) atomicAdd(&Y[(size_t)tok * H_DIM + col], v);
          else          Y[(size_t)tok * H_DIM + col] = v;
        }
      }
    }
  }
}

// ---------------- launch ----------------
extern "C" void kernel_launch(void* const* d_in, const int* in_sizes, int n_in,
                              void* d_out, int out_size, void* d_ws, size_t ws_size,
                              hipStream_t stream) {
  const float* x      = (const float*)d_in[0];
  const float* gate_w = (const float*)d_in[1];
  const float* wg     = (const float*)d_in[2];
  const float* wu     = (const float*)d_in[3];
  const float* wd     = (const float*)d_in[4];
  const float* swg    = (const float*)d_in[5];
  const float* swu    = (const float*)d_in[6];
  const float* swd    = (const float*)d_in[7];
  float* Y = (float*)d_out;
  char* ws = (char*)d_ws;

  constexpr size_t XB_SZ   = (size_t)T_TOK * H_DIM * 2;
  constexpr size_t WEXP_SZ = (size_t)E_NUM * I_DIM * H_DIM * 2;
  constexpr size_t SW_SZ   = (size_t)I_DIM * H_DIM * 2;
  constexpr size_t H_SZ    = (size_t)T_TOK * 2 * I_DIM * 2;

  constexpr size_t XB_OFF  = 0;
  constexpr size_t WG_OFF  = XB_OFF + XB_SZ;
  constexpr size_t WU_OFF  = WG_OFF + WEXP_SZ;
  constexpr size_t WD_OFF  = WU_OFF + WEXP_SZ;
  constexpr size_t SWG_OFF = WD_OFF + WEXP_SZ;
  constexpr size_t SWU_OFF = SWG_OFF + SW_SZ;
  constexpr size_t SWD_OFF = SWU_OFF + SW_SZ;
  constexpr size_t H_OFF   = SWD_OFF + SW_SZ;
  constexpr size_t META_OFF = H_OFF + H_SZ;
  constexpr size_t TI_OFF  = META_OFF;
  constexpr size_t TW_OFF  = TI_OFF + 65536;
  constexpr size_t PM_OFF  = TW_OFF + 65536;
  constexpr size_t PW_OFF  = PM_OFF + 65536;
  constexpr size_t CNT_OFF = PW_OFF + 65536;
  constexpr size_t NEEDED  = CNT_OFF + 4096;

  if (ws_size < NEEDED){
    fill_kernel<<<(out_size + 255) / 256, 256, 0, stream>>>(Y, 12345.0f, out_size);
    return;
  }

  ushort_t* xb   = (ushort_t*)(ws + XB_OFF);
  ushort_t* wgb  = (ushort_t*)(ws + WG_OFF);
  ushort_t* wub  = (ushort_t*)(ws + WU_OFF);
  ushort_t* wdb  = (ushort_t*)(ws + WD_OFF);
  ushort_t* swgb = (ushort_t*)(ws + SWG_OFF);
  ushort_t* swub = (ushort_t*)(ws + SWU_OFF);
  ushort_t* swdb = (ushort_t*)(ws + SWD_OFF);
  ushort_t* hb   = (ushort_t*)(ws + H_OFF);
  int*   topk_idx = (int*)(ws + TI_OFF);
  float* topk_w   = (float*)(ws + TW_OFF);
  int*   perm     = (int*)(ws + PM_OFF);
  float* pw       = (float*)(ws + PW_OFF);
  int*   counts   = (int*)(ws + CNT_OFF);
  int*   offs     = counts + 8;
  int*   cursor   = offs + 9;

  cvt_kernel<<<2048, 256, 0, stream>>>((const float4*)wg,  (ushort4*)wgb,  (int)(E_NUM * (size_t)I_DIM * H_DIM / 4));
  cvt_kernel<<<2048, 256, 0, stream>>>((const float4*)wu,  (ushort4*)wub,  (int)(E_NUM * (size_t)I_DIM * H_DIM / 4));
  cvt_kernel<<<2048, 256, 0, stream>>>((const float4*)wd,  (ushort4*)wdb,  (int)(E_NUM * (size_t)I_DIM * H_DIM / 4));
  cvt_kernel<<<1024, 256, 0, stream>>>((const float4*)swg, (ushort4*)swgb, (int)((size_t)I_DIM * H_DIM / 4));
  cvt_kernel<<<1024, 256, 0, stream>>>((const float4*)swu, (ushort4*)swub, (int)((size_t)I_DIM * H_DIM / 4));
  cvt_kernel<<<1024, 256, 0, stream>>>((const float4*)swd, (ushort4*)swdb, (int)((size_t)I_DIM * H_DIM / 4));

  hipMemsetAsync(counts, 0, 8 * sizeof(int), stream);
  gate_kernel<<<T_TOK / 4, 256, 0, stream>>>(x, gate_w, xb, topk_idx, topk_w, counts);
  offsets_kernel<<<1, 64, 0, stream>>>(counts, offs, cursor);
  scatter_kernel<<<T_TOK / 256, 256, 0, stream>>>(topk_idx, topk_w, cursor, perm, pw);

  // shared expert (writes y with '=', covering all of d_out)
  gemm1_kernel<<<dim3((I_DIM + 127) / 128, T_TOK / 256), 512, 0, stream>>>(
      xb, swgb, swub, hb, nullptr, nullptr, nullptr, T_TOK);
  gemm2_kernel<<<dim3(H_DIM / 256, T_TOK / 256), 512, 0, stream>>>(
      hb, swdb, Y, nullptr, nullptr, T_TOK, 0);

  // routed experts
  constexpr int MAX_TILES = (T_TOK * 2) / 256 + E_NUM;   // 72
  gemm1_kernel<<<dim3((I_DIM + 127) / 128, MAX_TILES), 512, 0, stream>>>(
      xb, wgb, wub, hb, offs, perm, pw, 0);
  gemm2_kernel<<<dim3(H_DIM / 256, MAX_TILES), 512, 0, stream>>>(
      hb, wdb, Y, offs, perm, 0, 1);
}

// Round 11
// 1023.492 us; speedup vs baseline: 1.0883x; 1.0883x over previous
//
#include <hip/hip_runtime.h>
#include <stdint.h>

#define T_TOK 8192
#define H_DIM 1024
#define I_DIM 2752
#define E_NUM 8

typedef unsigned short ushort_t;
typedef short bf16x8 __attribute__((ext_vector_type(8)));
typedef float f32x4 __attribute__((ext_vector_type(4)));

__device__ __forceinline__ unsigned short f2bf(float f){
  union { float f; uint32_t u; } v; v.f = f;
  return (unsigned short)((v.u + 0x7fffu + ((v.u >> 16) & 1u)) >> 16);
}
__device__ __forceinline__ float bf2f(unsigned short b){
  union { uint32_t u; float f; } v; v.u = ((uint32_t)b) << 16;
  return v.f;
}

__device__ __forceinline__ void gload16(const ushort_t* g, ushort_t* l){
  __builtin_amdgcn_global_load_lds(
      (const __attribute__((address_space(1))) void*)g,
      (__attribute__((address_space(3))) void*)l, 16, 0, 0);
}

// ---------------- convert fp32 -> bf16 ----------------
__global__ void cvt_kernel(const float4* __restrict__ src, ushort4* __restrict__ dst, int n4){
  int stride = gridDim.x * blockDim.x;
  for (int i = blockIdx.x * blockDim.x + threadIdx.x; i < n4; i += stride){
    float4 v = src[i];
    ushort4 o;
    o.x = f2bf(v.x); o.y = f2bf(v.y); o.z = f2bf(v.z); o.w = f2bf(v.w);
    dst[i] = o;
  }
}

__global__ void fill_kernel(float* __restrict__ p, float v, int n){
  int i = blockIdx.x * blockDim.x + threadIdx.x;
  if (i < n) p[i] = v;
}

// ---------------- gate: fp32 logits, softmax-top2; also emits x in bf16 ----------------
__global__ void gate_kernel(const float* __restrict__ x, const float* __restrict__ gw,
                            ushort_t* __restrict__ xb,
                            int* __restrict__ topk_idx, float* __restrict__ topk_w,
                            int* __restrict__ counts){
  int lane = threadIdx.x & 63;
  int wv = threadIdx.x >> 6;
  int t = blockIdx.x * 4 + wv;
  const float* xt = x + (size_t)t * H_DIM;
  ushort_t* xbt = xb + (size_t)t * H_DIM;
  float acc[E_NUM];
  #pragma unroll
  for (int e = 0; e < E_NUM; e++) acc[e] = 0.f;
  for (int c = 0; c < H_DIM / 64; c++){
    float xv = xt[c * 64 + lane];
    xbt[c * 64 + lane] = f2bf(xv);
    #pragma unroll
    for (int e = 0; e < E_NUM; e++) acc[e] += xv * gw[e * H_DIM + c * 64 + lane];
  }
  #pragma unroll
  for (int e = 0; e < E_NUM; e++){
    #pragma unroll
    for (int o = 32; o; o >>= 1) acc[e] += __shfl_xor(acc[e], o);
  }
  if (lane == 0){
    int i1 = 0; float l1 = acc[0];
    #pragma unroll
    for (int e = 1; e < E_NUM; e++) if (acc[e] > l1){ l1 = acc[e]; i1 = e; }
    int i2 = -1; float l2 = -1e30f;
    #pragma unroll
    for (int e = 0; e < E_NUM; e++) if (e != i1 && acc[e] > l2){ l2 = acc[e]; i2 = e; }
    float e2 = expf(l2 - l1);
    float denom = 1.0f + e2;
    topk_idx[t * 2 + 0] = i1; topk_idx[t * 2 + 1] = i2;
    topk_w[t * 2 + 0] = 1.0f / denom; topk_w[t * 2 + 1] = e2 / denom;
    atomicAdd(&counts[i1], 1); atomicAdd(&counts[i2], 1);
  }
}

__global__ void offsets_kernel(const int* __restrict__ counts, int* __restrict__ offs,
                               int* __restrict__ cursor){
  if (threadIdx.x == 0 && blockIdx.x == 0){
    int a = 0;
    for (int e = 0; e < E_NUM; e++){ offs[e] = a; cursor[e] = a; a += counts[e]; }
    offs[E_NUM] = a;
  }
}

__global__ void scatter_kernel(const int* __restrict__ topk_idx, const float* __restrict__ topk_w,
                               int* __restrict__ cursor, int* __restrict__ perm,
                               float* __restrict__ pw, int* __restrict__ ip){
  int t = blockIdx.x * blockDim.x + threadIdx.x;
  if (t >= T_TOK) return;
  #pragma unroll
  for (int k = 0; k < 2; k++){
    int e = topk_idx[t * 2 + k];
    int pos = atomicAdd(&cursor[e], 1);
    perm[pos] = t;
    pw[pos] = topk_w[t * 2 + k];
    ip[t * 2 + k] = pos;
  }
}

// combine: y[t] += Yp[ip0[t]] + Yp[ip1[t]]   (bf16 gathers, coalesced rows)
__global__ void combine_kernel(float* __restrict__ Y, const ushort_t* __restrict__ Yp,
                               const int* __restrict__ ip){
  int idx = blockIdx.x * blockDim.x + threadIdx.x;   // over T*H/8
  int t = idx >> 7;                                  // H/8 = 128
  int c8 = (idx & 127) << 3;
  int p0 = ip[t * 2], p1 = ip[t * 2 + 1];
  bf16x8 v0 = *(const bf16x8*)(Yp + (size_t)p0 * H_DIM + c8);
  bf16x8 v1 = *(const bf16x8*)(Yp + (size_t)p1 * H_DIM + c8);
  float* y = Y + (size_t)t * H_DIM + c8;
  #pragma unroll
  for (int j = 0; j < 8; j++)
    y[j] += bf2f((unsigned short)v0[j]) + bf2f((unsigned short)v1[j]);
}

// helper: resolve grouped tile (BM=256)
__device__ __forceinline__ bool resolve_tile(const int* offs, int fixedM, int bx,
                                             int& e, int& row0, int& mEnd, int& maxRow){
  e = 0; row0 = 0; mEnd = fixedM; maxRow = fixedM - 1;
  if (offs){
    int base = 0; bool found = false;
    for (e = 0; e < E_NUM; ++e){
      int m0 = offs[e], m1 = offs[e + 1];
      int nt = (m1 - m0 + 255) >> 8;
      if (bx < base + nt){ row0 = m0 + (bx - base) * 256; mEnd = m1; found = true; break; }
      base += nt;
    }
    if (!found) return false;
    maxRow = offs[E_NUM] - 1;
    if (maxRow < 0) return false;
  } else {
    row0 = bx * 256;
  }
  return true;
}

// ---------------- GEMM1: h = silu(X@Wg^T) * (X@Wu^T) * route_w ----------------
// r5 schedule (best verified): BM=256 x BN=128 (dual B), BK=64, 8 waves 4Mx2N,
// 2-deep LDS ring, full-tile prefetch + vmcnt(8), 2 barriers/K-tile, T2 swizzle.
__global__ __launch_bounds__(512, 2) void gemm1_kernel(
    const ushort_t* __restrict__ Xb,
    const ushort_t* __restrict__ Wg,
    const ushort_t* __restrict__ Wu,
    ushort_t* __restrict__ Hb,
    const int* __restrict__ offs,
    const int* __restrict__ perm,
    const float* __restrict__ pw,
    int fixedM)
{
  __shared__ __align__(16) ushort_t ldsA[2 * 16384];
  __shared__ __align__(16) ushort_t ldsG[2 * 8192];
  __shared__ __align__(16) ushort_t ldsU[2 * 8192];

  const int tid = threadIdx.x;
  const int lane = tid & 63;
  const int wv = tid >> 6;        // 0..7
  const int wm = wv >> 1;         // 0..3 (M)
  const int wn = wv & 1;          // 0..1 (N)

  int e, row0, mEnd, maxRow;
  if (!resolve_tile(offs, fixedM, blockIdx.y, e, row0, mEnd, maxRow)) return;

  const ushort_t* Weg = Wg + (size_t)e * I_DIM * H_DIM;
  const ushort_t* Weu = Wu + (size_t)e * I_DIM * H_DIM;
  const int nb = blockIdx.x * 128;

  const int sr = tid >> 3;                   // row-in-issue 0..63
  const int sc = (tid & 7) ^ (sr & 7);       // swizzled source chunk
  const ushort_t* sA[4];
  const ushort_t* sG[2];
  const ushort_t* sU[2];
  #pragma unroll
  for (int i = 0; i < 4; i++){
    int gr = row0 + i * 64 + sr;
    if (gr > maxRow) gr = maxRow;
    int tok = perm ? perm[gr] : gr;
    sA[i] = Xb + (size_t)tok * H_DIM + sc * 8;
  }
  #pragma unroll
  for (int i = 0; i < 2; i++){
    int n = nb + i * 64 + sr;
    if (n > I_DIM - 1) n = I_DIM - 1;
    sG[i] = Weg + (size_t)n * H_DIM + sc * 8;
    sU[i] = Weu + (size_t)n * H_DIM + sc * 8;
  }
  const int dstOff = wv * 512;

  const int x0 = (((lane >> 4) + 0) ^ (lane & 7)) << 3;
  const int x1 = (((lane >> 4) + 4) ^ (lane & 7)) << 3;
  const int rowA = (wm * 64 + (lane & 15)) * 64;
  const int rowB = (wn * 64 + (lane & 15)) * 64;

  f32x4 accg[4][4], accu[4][4];
  const f32x4 zero = {0.f, 0.f, 0.f, 0.f};
  #pragma unroll
  for (int m = 0; m < 4; m++)
    #pragma unroll
    for (int n = 0; n < 4; n++){ accg[m][n] = zero; accu[m][n] = zero; }

  constexpr int NT = H_DIM / 64;   // 16

  #pragma unroll
  for (int i = 0; i < 4; i++) gload16(sA[i], ldsA + i * 4096 + dstOff);
  #pragma unroll
  for (int i = 0; i < 2; i++) gload16(sG[i], ldsG + i * 4096 + dstOff);
  #pragma unroll
  for (int i = 0; i < 2; i++) gload16(sU[i], ldsU + i * 4096 + dstOff);

  #pragma unroll 1
  for (int t = 0; t < NT; ++t){
    const int t1 = (t + 1 < NT) ? t + 1 : NT - 1;
    const int k1 = t1 * 64;
    const int sel  = (t & 1);
    const int sel1 = sel ^ 1;

    #pragma unroll
    for (int i = 0; i < 4; i++) gload16(sA[i] + k1, ldsA + sel1 * 16384 + i * 4096 + dstOff);
    #pragma unroll
    for (int i = 0; i < 2; i++) gload16(sG[i] + k1, ldsG + sel1 * 8192 + i * 4096 + dstOff);
    #pragma unroll
    for (int i = 0; i < 2; i++) gload16(sU[i] + k1, ldsU + sel1 * 8192 + i * 4096 + dstOff);

    asm volatile("s_waitcnt vmcnt(8)" ::: "memory");
    __builtin_amdgcn_s_barrier();
    __builtin_amdgcn_sched_barrier(0);

    const ushort_t* pA = ldsA + sel * 16384 + rowA;
    const ushort_t* pG = ldsG + sel * 8192 + rowB;
    const ushort_t* pU = ldsU + sel * 8192 + rowB;

    bf16x8 a[4], bg[4], bu[4];
    #pragma unroll
    for (int ks = 0; ks < 2; ks++){
      const int x = ks ? x1 : x0;
      #pragma unroll
      for (int m = 0; m < 4; m++) a[m]  = *(const bf16x8*)(pA + m * 1024 + x);
      #pragma unroll
      for (int n = 0; n < 4; n++) bg[n] = *(const bf16x8*)(pG + n * 1024 + x);
      #pragma unroll
      for (int n = 0; n < 4; n++) bu[n] = *(const bf16x8*)(pU + n * 1024 + x);
      __builtin_amdgcn_s_setprio(1);
      #pragma unroll
      for (int m = 0; m < 4; m++)
        #pragma unroll
        for (int n = 0; n < 4; n++){
          accg[m][n] = __builtin_amdgcn_mfma_f32_16x16x32_bf16(a[m], bg[n], accg[m][n], 0, 0, 0);
          accu[m][n] = __builtin_amdgcn_mfma_f32_16x16x32_bf16(a[m], bu[n], accu[m][n], 0, 0, 0);
        }
      __builtin_amdgcn_s_setprio(0);
    }
    __builtin_amdgcn_s_barrier();
  }
  asm volatile("s_waitcnt vmcnt(0)" ::: "memory");

  // epilogue: silu(g)*u*wt -> bf16 h
  #pragma unroll
  for (int m = 0; m < 4; m++){
    #pragma unroll
    for (int j = 0; j < 4; j++){
      int gr = row0 + wm * 64 + m * 16 + ((lane >> 4) << 2) + j;
      if (gr < mEnd){
        float wt = pw ? pw[gr] : 1.0f;
        ushort_t* hrow = Hb + (size_t)gr * I_DIM;
        #pragma unroll
        for (int n = 0; n < 4; n++){
          int c = nb + wn * 64 + n * 16 + (lane & 15);
          if (c < I_DIM){
            float gv = accg[m][n][j];
            float uv = accu[m][n][j];
            float hv = (gv / (1.0f + __expf(-gv))) * uv * wt;
            hrow[c] = f2bf(hv);
          }
        }
      }
    }
  }
}

// ---------------- GEMM2: down-proj ----------------
// BM=256 x BN=256, BK=64, 8 waves 2Mx4N, r5 schedule.
// mode 0: plain f32 store to Y (token order)   [shared expert]
// mode 1: f32 atomicAdd to Y (token order)     [routed fallback]
// mode 2: bf16 plain store to Yp (perm order)  [routed, no atomics]
__global__ __launch_bounds__(512, 2) void gemm2_kernel(
    const ushort_t* __restrict__ Hb,
    const ushort_t* __restrict__ Wd,
    float* __restrict__ Y,
    ushort_t* __restrict__ Yp,
    const int* __restrict__ offs,
    const int* __restrict__ perm,
    int fixedM, int mode)
{
  __shared__ __align__(16) ushort_t ldsA[2 * 16384];
  __shared__ __align__(16) ushort_t ldsB[2 * 16384];

  const int tid = threadIdx.x;
  const int lane = tid & 63;
  const int wv = tid >> 6;
  const int wm = wv >> 2;          // 0..1
  const int wn = wv & 3;           // 0..3

  int e, row0, mEnd, maxRow;
  if (!resolve_tile(offs, fixedM, blockIdx.y, e, row0, mEnd, maxRow)) return;

  const ushort_t* Wde = Wd + (size_t)e * H_DIM * I_DIM;
  const int nb = blockIdx.x * 256;

  const int sr = tid >> 3;
  const int sc = (tid & 7) ^ (sr & 7);
  const ushort_t* sA[4];
  const ushort_t* sB[4];
  #pragma unroll
  for (int i = 0; i < 4; i++){
    int gr = row0 + i * 64 + sr;
    if (gr > maxRow) gr = maxRow;
    sA[i] = Hb + (size_t)gr * I_DIM + sc * 8;
    int n = nb + i * 64 + sr;      // < 1024 always
    sB[i] = Wde + (size_t)n * I_DIM + sc * 8;
  }
  const int dstOff = wv * 512;

  const int x0 = (((lane >> 4) + 0) ^ (lane & 7)) << 3;
  const int x1 = (((lane >> 4) + 4) ^ (lane & 7)) << 3;
  const int rowA = (wm * 128 + (lane & 15)) * 64;
  const int rowB = (wn * 64 + (lane & 15)) * 64;

  f32x4 acc[8][4];
  const f32x4 zero = {0.f, 0.f, 0.f, 0.f};
  #pragma unroll
  for (int m = 0; m < 8; m++)
    #pragma unroll
    for (int n = 0; n < 4; n++) acc[m][n] = zero;

  constexpr int NT = I_DIM / 64;   // 43

  #pragma unroll
  for (int i = 0; i < 4; i++) gload16(sA[i], ldsA + i * 4096 + dstOff);
  #pragma unroll
  for (int i = 0; i < 4; i++) gload16(sB[i], ldsB + i * 4096 + dstOff);

  #pragma unroll 1
  for (int t = 0; t < NT; ++t){
    const int t1 = (t + 1 < NT) ? t + 1 : NT - 1;
    const int k1 = t1 * 64;
    const int sel  = (t & 1);
    const int sel1 = sel ^ 1;

    #pragma unroll
    for (int i = 0; i < 4; i++) gload16(sA[i] + k1, ldsA + sel1 * 16384 + i * 4096 + dstOff);
    #pragma unroll
    for (int i = 0; i < 4; i++) gload16(sB[i] + k1, ldsB + sel1 * 16384 + i * 4096 + dstOff);

    asm volatile("s_waitcnt vmcnt(8)" ::: "memory");
    __builtin_amdgcn_s_barrier();
    __builtin_amdgcn_sched_barrier(0);

    const ushort_t* pA = ldsA + sel * 16384 + rowA;
    const ushort_t* pB = ldsB + sel * 16384 + rowB;

    bf16x8 a[8], b[4];
    #pragma unroll
    for (int ks = 0; ks < 2; ks++){
      const int x = ks ? x1 : x0;
      #pragma unroll
      for (int m = 0; m < 8; m++) a[m] = *(const bf16x8*)(pA + m * 1024 + x);
      #pragma unroll
      for (int n = 0; n < 4; n++) b[n] = *(const bf16x8*)(pB + n * 1024 + x);
      __builtin_amdgcn_s_setprio(1);
      #pragma unroll
      for (int m = 0; m < 8; m++)
        #pragma unroll
        for (int n = 0; n < 4; n++)
          acc[m][n] = __builtin_amdgcn_mfma_f32_16x16x32_bf16(a[m], b[n], acc[m][n], 0, 0, 0);
      __builtin_amdgcn_s_setprio(0);
    }
    __builtin_amdgcn_s_barrier();
  }
  asm volatile("s_waitcnt vmcnt(0)" ::: "memory");

  #pragma unroll
  for (int m = 0; m < 8; m++){
    #pragma unroll
    for (int j = 0; j < 4; j++){
      int gr = row0 + wm * 128 + m * 16 + ((lane >> 4) << 2) + j;
      if (gr < mEnd){
        if (mode == 2){
          ushort_t* yrow = Yp + (size_t)gr * H_DIM;
          #pragma unroll
          for (int n = 0; n < 4; n++){
            int c = nb + wn * 64 + n * 16 + (lane & 15);
            yrow[c] = f2bf(acc[m][n][j]);
          }
        } else {
          int tok = perm ? perm[gr] : gr;
          float* yrow = Y + (size_t)tok * H_DIM;
          #pragma unroll
          for (int n = 0; n < 4; n++){
            int c = nb + wn * 64 + n * 16 + (lane & 15);
            float v = acc[m][n][j];
            if (mode == 1) atomicAdd(&yrow[c], v);
            else           yrow[c] = v;
          }
        }
      }
    }
  }
}

// ---------------- launch ----------------
extern "C" void kernel_launch(void* const* d_in, const int* in_sizes, int n_in,
                              void* d_out, int out_size, void* d_ws, size_t ws_size,
                              hipStream_t stream) {
  const float* x      = (const float*)d_in[0];
  const float* gate_w = (const float*)d_in[1];
  const float* wg     = (const float*)d_in[2];
  const float* wu     = (const float*)d_in[3];
  const float* wd     = (const float*)d_in[4];
  const float* swg    = (const float*)d_in[5];
  const float* swu    = (const float*)d_in[6];
  const float* swd    = (const float*)d_in[7];
  float* Y = (float*)d_out;
  char* ws = (char*)d_ws;

  constexpr size_t XB_SZ   = (size_t)T_TOK * H_DIM * 2;
  constexpr size_t WEXP_SZ = (size_t)E_NUM * I_DIM * H_DIM * 2;
  constexpr size_t SW_SZ   = (size_t)I_DIM * H_DIM * 2;
  constexpr size_t H_SZ    = (size_t)T_TOK * 2 * I_DIM * 2;
  constexpr size_t YP_SZ   = (size_t)T_TOK * 2 * H_DIM * 2;   // 33,554,432

  constexpr size_t XB_OFF  = 0;
  constexpr size_t WG_OFF  = XB_OFF + XB_SZ;
  constexpr size_t WU_OFF  = WG_OFF + WEXP_SZ;
  constexpr size_t WD_OFF  = WU_OFF + WEXP_SZ;
  constexpr size_t SWG_OFF = WD_OFF + WEXP_SZ;
  constexpr size_t SWU_OFF = SWG_OFF + SW_SZ;
  constexpr size_t SWD_OFF = SWU_OFF + SW_SZ;
  constexpr size_t H_OFF   = SWD_OFF + SW_SZ;
  constexpr size_t META_OFF = H_OFF + H_SZ;
  constexpr size_t TI_OFF  = META_OFF;
  constexpr size_t TW_OFF  = TI_OFF + 65536;
  constexpr size_t PM_OFF  = TW_OFF + 65536;
  constexpr size_t PW_OFF  = PM_OFF + 65536;
  constexpr size_t IP_OFF  = PW_OFF + 65536;
  constexpr size_t CNT_OFF = IP_OFF + 65536;
  constexpr size_t NEEDED_BASE = CNT_OFF + 4096;
  constexpr size_t YP_OFF  = NEEDED_BASE;
  constexpr size_t NEEDED_FULL = YP_OFF + YP_SZ;

  if (ws_size < NEEDED_BASE){
    fill_kernel<<<(out_size + 255) / 256, 256, 0, stream>>>(Y, 12345.0f, out_size);
    return;
  }
  const bool haveYp = (ws_size >= NEEDED_FULL);

  ushort_t* xb   = (ushort_t*)(ws + XB_OFF);
  ushort_t* wgb  = (ushort_t*)(ws + WG_OFF);
  ushort_t* wub  = (ushort_t*)(ws + WU_OFF);
  ushort_t* wdb  = (ushort_t*)(ws + WD_OFF);
  ushort_t* swgb = (ushort_t*)(ws + SWG_OFF);
  ushort_t* swub = (ushort_t*)(ws + SWU_OFF);
  ushort_t* swdb = (ushort_t*)(ws + SWD_OFF);
  ushort_t* hb   = (ushort_t*)(ws + H_OFF);
  ushort_t* yp   = (ushort_t*)(ws + YP_OFF);
  int*   topk_idx = (int*)(ws + TI_OFF);
  float* topk_w   = (float*)(ws + TW_OFF);
  int*   perm     = (int*)(ws + PM_OFF);
  float* pw       = (float*)(ws + PW_OFF);
  int*   ip       = (int*)(ws + IP_OFF);
  int*   counts   = (int*)(ws + CNT_OFF);
  int*   offs     = counts + 8;
  int*   cursor   = offs + 9;

  cvt_kernel<<<2048, 256, 0, stream>>>((const float4*)wg,  (ushort4*)wgb,  (int)(E_NUM * (size_t)I_DIM * H_DIM / 4));
  cvt_kernel<<<2048, 256, 0, stream>>>((const float4*)wu,  (ushort4*)wub,  (int)(E_NUM * (size_t)I_DIM * H_DIM / 4));
  cvt_kernel<<<2048, 256, 0, stream>>>((const float4*)wd,  (ushort4*)wdb,  (int)(E_NUM * (size_t)I_DIM * H_DIM / 4));
  cvt_kernel<<<1024, 256, 0, stream>>>((const float4*)swg, (ushort4*)swgb, (int)((size_t)I_DIM * H_DIM / 4));
  cvt_kernel<<<1024, 256, 0, stream>>>((const float4*)swu, (ushort4*)swub, (int)((size_t)I_DIM * H_DIM / 4));
  cvt_kernel<<<1024, 256, 0, stream>>>((const float4*)swd, (ushort4*)swdb, (int)((size_t)I_DIM * H_DIM / 4));

  hipMemsetAsync(counts, 0, 8 * sizeof(int), stream);
  gate_kernel<<<T_TOK / 4, 256, 0, stream>>>(x, gate_w, xb, topk_idx, topk_w, counts);
  offsets_kernel<<<1, 64, 0, stream>>>(counts, offs, cursor);
  scatter_kernel<<<T_TOK / 256, 256, 0, stream>>>(topk_idx, topk_w, cursor, perm, pw, ip);

  // shared expert (writes y with '=', covering all of d_out)
  gemm1_kernel<<<dim3((I_DIM + 127) / 128, T_TOK / 256), 512, 0, stream>>>(
      xb, swgb, swub, hb, nullptr, nullptr, nullptr, T_TOK);
  gemm2_kernel<<<dim3(H_DIM / 256, T_TOK / 256), 512, 0, stream>>>(
      hb, swdb, Y, nullptr, nullptr, nullptr, T_TOK, 0);

  // routed experts
  constexpr int MAX_TILES = (T_TOK * 2) / 256 + E_NUM;   // 72
  gemm1_kernel<<<dim3((I_DIM + 127) / 128, MAX_TILES), 512, 0, stream>>>(
      xb, wgb, wub, hb, offs, perm, pw, 0);
  if (haveYp){
    gemm2_kernel<<<dim3(H_DIM / 256, MAX_TILES), 512, 0, stream>>>(
        hb, wdb, Y, yp, offs, perm, 0, 2);
    combine_kernel<<<(T_TOK * H_DIM / 8) / 256, 256, 0, stream>>>(Y, yp, ip);
  } else {
    gemm2_kernel<<<dim3(H_DIM / 256, MAX_TILES), 512, 0, stream>>>(
        hb, wdb, Y, nullptr, offs, perm, 0, 1);
  }
}